// Round 2
// baseline (152.079 us; speedup 1.0000x reference)
//
#include <hip/hip_runtime.h>
#include <hip/hip_bf16.h>

#define B_SZ 8192
#define D_SZ 256
#define NT_WAVE 4160   // per-wave 128x64 tiles covering upper triangle: sum_{bi<64}(128-2bi)
// rows pre-scaled by sqrt(log2(e)/T): exp2(acc) == exp(sim/T)
#define PRESCALE 4.539816004686735f

typedef __attribute__((ext_vector_type(4))) float f32x4;
typedef __attribute__((ext_vector_type(8))) short s16x8;

// Fragment-major storage of normalized bf16 matrix N' (written by norm_kernel):
//   fragment f = (row>>4)*8 + (k>>5)          (16 rows x 32 k  = one MFMA operand)
//   lane  l = (row&15) + (((k>>3)&3)<<4)      (matches mfma_f32_16x16x32_bf16 A/B layout)
//   ushort offset = f*512 + l*8 + (k&7)
// A fragment load is then ONE coalesced global_load_dwordx4 at base + lane*16.

// ---------------- L2-normalize rows, scale, cast to bf16 (+ zero sums) -----
__global__ __launch_bounds__(256) void norm_kernel(const float* __restrict__ emb,
                                                   ushort* __restrict__ nbf,
                                                   float* __restrict__ sums) {
    // zero all_sum+pos_sum: 16384 floats over 256 blocks
    sums[blockIdx.x * 64 + (threadIdx.x >> 2)] = 0.0f;

    const int wave = threadIdx.x >> 6, lane = threadIdx.x & 63;
    for (int g = blockIdx.x; g < B_SZ / 4; g += 256) {
        const int row = g * 4 + wave;
        const float4 v = ((const float4*)(emb + (size_t)row * D_SZ))[lane];
        float ss = v.x * v.x + v.y * v.y + v.z * v.z + v.w * v.w;
        #pragma unroll
        for (int m = 1; m < 64; m <<= 1) ss += __shfl_xor(ss, m, 64);
        float s = PRESCALE / fmaxf(sqrtf(ss), 1e-12f);
        __hip_bfloat16 b0 = __float2bfloat16(v.x * s);
        __hip_bfloat16 b1 = __float2bfloat16(v.y * s);
        __hip_bfloat16 b2 = __float2bfloat16(v.z * s);
        __hip_bfloat16 b3 = __float2bfloat16(v.w * s);
        ushort4 o;
        o.x = *(ushort*)&b0; o.y = *(ushort*)&b1; o.z = *(ushort*)&b2; o.w = *(ushort*)&b3;
        // fragment-major destination for k0..k0+3
        const int k0 = lane * 4;
        const int f  = (row >> 4) * 8 + (k0 >> 5);
        const int sl = (row & 15) + (((k0 >> 3) & 3) << 4);
        *(ushort4*)(nbf + (size_t)f * 512 + sl * 8 + (k0 & 7)) = o;
    }
}

// ---------------- tile decode: tb -> (bi, bj), bj >= 2*bi -------------------
// strip bi holds tiles bj = 2bi..127 (count 128-2bi); offset o(bi) = bi*(129-bi)
__device__ __forceinline__ void decode_tile(int tb, int& i0, int& j0, bool& straddle) {
    int bi = (int)((129.0f - sqrtf(16641.0f - 4.0f * (float)tb)) * 0.5f);
    while ((bi + 1) * (129 - (bi + 1)) <= tb) ++bi;
    while (bi * (129 - bi) > tb) --bi;
    const int bj = 2 * bi + (tb - bi * (129 - bi));
    i0 = bi * 128; j0 = bj * 64;
    straddle = (bj - 2 * bi) < 2;
}

// ---------------- epilogue: exp2, masked row/col sums, shfl-reduce, atomics -
template <bool MASK>
__device__ __forceinline__ void do_epilogue(const f32x4 (&acc)[8][4],
                                            const int* __restrict__ ids,
                                            float* __restrict__ all_sum,
                                            float* __restrict__ pos_sum,
                                            int i0, int j0, int hi, int myc) {
    int idc[4];
    #pragma unroll
    for (int ni = 0; ni < 4; ++ni) idc[ni] = ids[j0 + ni * 16 + myc];

    float cA[4] = {0.f, 0.f, 0.f, 0.f};
    float cP[4] = {0.f, 0.f, 0.f, 0.f};

    #pragma unroll
    for (int mi = 0; mi < 8; ++mi) {
        const int rbase = i0 + mi * 16 + hi * 4;
        const int4 idr = *(const int4*)&ids[rbase];
        float rA[4] = {0.f, 0.f, 0.f, 0.f};
        float rP[4] = {0.f, 0.f, 0.f, 0.f};
        #pragma unroll
        for (int ni = 0; ni < 4; ++ni) {
            const int gj = j0 + ni * 16 + myc;
            #pragma unroll
            for (int rg = 0; rg < 4; ++rg) {
                float e = __builtin_amdgcn_exp2f(acc[mi][ni][rg]);
                if (MASK) { if (gj <= rbase + rg) e = 0.0f; }   // lower-tri + diagonal
                const int idrv = (rg == 0) ? idr.x : (rg == 1) ? idr.y
                               : (rg == 2) ? idr.z : idr.w;
                rA[rg] += e; cA[ni] += e;
                if (idrv == idc[ni]) { rP[rg] += e; cP[ni] += e; }
            }
        }
        // row sums: butterfly over the 16 lanes of this hi-group
        #pragma unroll
        for (int rg = 0; rg < 4; ++rg) {
            #pragma unroll
            for (int m = 1; m < 16; m <<= 1) {
                rA[rg] += __shfl_xor(rA[rg], m, 64);
                rP[rg] += __shfl_xor(rP[rg], m, 64);
            }
        }
        if (myc == 0) {
            #pragma unroll
            for (int rg = 0; rg < 4; ++rg) {
                atomicAdd(&all_sum[rbase + rg], rA[rg]);
                if (rP[rg] != 0.0f) atomicAdd(&pos_sum[rbase + rg], rP[rg]);
            }
        }
    }

    // column sums -> symmetric contribution to rows j (j>i elements only)
    #pragma unroll
    for (int ni = 0; ni < 4; ++ni) {
        cA[ni] += __shfl_xor(cA[ni], 16, 64);
        cA[ni] += __shfl_xor(cA[ni], 32, 64);
        cP[ni] += __shfl_xor(cP[ni], 16, 64);
        cP[ni] += __shfl_xor(cP[ni], 32, 64);
    }
    if (hi == 0) {
        #pragma unroll
        for (int ni = 0; ni < 4; ++ni) {
            atomicAdd(&all_sum[j0 + ni * 16 + myc], cA[ni]);
            if (cP[ni] != 0.0f) atomicAdd(&pos_sum[j0 + ni * 16 + myc], cP[ni]);
        }
    }
}

// ---------------- sim: LDS-free, per-wave independent 128x64 tiles ----------
// Fragments load straight from L2 (fragment-major nbf) -> no staging, no
// barriers, no LDS. Traffic: (128+64)*256*2B = 96 KB / 8192 outputs
// = 12 B/elem (vs 16 with the 2x2-wave LDS scheme).
__global__ __launch_bounds__(256, 2) void sim_kernel(const ushort* __restrict__ N,
                                                     const int* __restrict__ ids,
                                                     float* __restrict__ all_sum,
                                                     float* __restrict__ pos_sum) {
    const int wave = threadIdx.x >> 6, lane = threadIdx.x & 63;
    const int hi = lane >> 4, myc = lane & 15;

    const int tb = blockIdx.x * 4 + wave;     // 1040 blocks * 4 waves = 4160
    int i0, j0; bool straddle;
    decode_tile(tb, i0, j0, straddle);

    f32x4 acc[8][4];
    #pragma unroll
    for (int mi = 0; mi < 8; ++mi)
        #pragma unroll
        for (int ni = 0; ni < 4; ++ni)
            acc[mi][ni] = (f32x4){0.f, 0.f, 0.f, 0.f};

    const ushort* Ap = N + (size_t)((i0 >> 4) * 8) * 512 + (size_t)lane * 8;
    const ushort* Bp = N + (size_t)((j0 >> 4) * 8) * 512 + (size_t)lane * 8;

    #pragma unroll 1
    for (int kc = 0; kc < 8; ++kc) {
        s16x8 bfr[4];
        #pragma unroll
        for (int ni = 0; ni < 4; ++ni)
            bfr[ni] = *(const s16x8*)(Bp + (size_t)(ni * 8 + kc) * 512);
        #pragma unroll
        for (int mi = 0; mi < 8; ++mi) {
            const s16x8 afr = *(const s16x8*)(Ap + (size_t)(mi * 8 + kc) * 512);
            #pragma unroll
            for (int ni = 0; ni < 4; ++ni)
                acc[mi][ni] = __builtin_amdgcn_mfma_f32_16x16x32_bf16(
                    afr, bfr[ni], acc[mi][ni], 0, 0, 0);
        }
    }

    if (straddle) do_epilogue<true >(acc, ids, all_sum, pos_sum, i0, j0, hi, myc);
    else          do_epilogue<false>(acc, ids, all_sum, pos_sum, i0, j0, hi, myc);
}

// ---------------- final scalar reduce ----------------
__global__ __launch_bounds__(256) void loss_kernel(const float* __restrict__ all_sum,
                                                   const float* __restrict__ pos_sum,
                                                   float* __restrict__ out) {
    float loss = 0.0f, cnt = 0.0f;
    for (int i = threadIdx.x; i < B_SZ; i += 256) {
        float p = pos_sum[i], a = all_sum[i];
        if (p > 0.0f) { loss += logf(a) - logf(p); cnt += 1.0f; }
    }
    #pragma unroll
    for (int m = 1; m < 64; m <<= 1) {
        loss += __shfl_xor(loss, m, 64);
        cnt  += __shfl_xor(cnt, m, 64);
    }
    __shared__ float sl[4], sc[4];
    int wave = threadIdx.x >> 6, lane = threadIdx.x & 63;
    if (lane == 0) { sl[wave] = loss; sc[wave] = cnt; }
    __syncthreads();
    if (threadIdx.x == 0) {
        float L = sl[0] + sl[1] + sl[2] + sl[3];
        float C = sc[0] + sc[1] + sc[2] + sc[3];
        out[0] = L / fmaxf(C, 1.0f);
    }
}

extern "C" void kernel_launch(void* const* d_in, const int* in_sizes, int n_in,
                              void* d_out, int out_size, void* d_ws, size_t ws_size,
                              hipStream_t stream) {
    const float* emb = (const float*)d_in[0];
    const int*   ids = (const int*)d_in[1];
    float*       out = (float*)d_out;

    float*  all_sum = (float*)d_ws;
    float*  pos_sum = all_sum + B_SZ;
    ushort* nbf     = (ushort*)((char*)d_ws + 65536);   // 8192*256 bf16 = 4 MB

    norm_kernel<<<256, 256, 0, stream>>>(emb, nbf, all_sum);
    sim_kernel<<<NT_WAVE / 4, 256, 0, stream>>>(nbf, ids, all_sum, pos_sum);
    loss_kernel<<<1, 256, 0, stream>>>(all_sum, pos_sum, out);
}

// Round 3
// 118.210 us; speedup vs baseline: 1.2865x; 1.2865x over previous
//
#include <hip/hip_runtime.h>
#include <hip/hip_bf16.h>

#define B_SZ 8192
#define D_SZ 256
#define NTILES 2080   // (8192/128)*(8192/128+1)/2 upper-tri tiles
#define GRID_SIM 512  // persistent, 2 blocks/CU (64 KB LDS)
// rows pre-scaled by sqrt(log2(e)/T): exp2(acc) == exp(sim/T)
#define PRESCALE 4.539816004686735f

typedef __attribute__((ext_vector_type(4))) float f32x4;
typedef __attribute__((ext_vector_type(8))) short s16x8;

// ---------------- L2-normalize rows, scale, cast to bf16 (+ zero sums) -----
__global__ __launch_bounds__(256) void norm_kernel(const float* __restrict__ emb,
                                                   ushort* __restrict__ nbf,
                                                   float* __restrict__ sums) {
    // zero all_sum+pos_sum: 16384 floats over 256 blocks
    sums[blockIdx.x * 64 + (threadIdx.x >> 2)] = 0.0f;

    const int wave = threadIdx.x >> 6, lane = threadIdx.x & 63;
    for (int g = blockIdx.x; g < B_SZ / 4; g += 256) {
        const int row = g * 4 + wave;
        const float4 v = ((const float4*)(emb + (size_t)row * D_SZ))[lane];
        float ss = v.x * v.x + v.y * v.y + v.z * v.z + v.w * v.w;
        #pragma unroll
        for (int m = 1; m < 64; m <<= 1) ss += __shfl_xor(ss, m, 64);
        float s = PRESCALE / fmaxf(sqrtf(ss), 1e-12f);
        __hip_bfloat16 b0 = __float2bfloat16(v.x * s);
        __hip_bfloat16 b1 = __float2bfloat16(v.y * s);
        __hip_bfloat16 b2 = __float2bfloat16(v.z * s);
        __hip_bfloat16 b3 = __float2bfloat16(v.w * s);
        ushort4 o;
        o.x = *(ushort*)&b0; o.y = *(ushort*)&b1; o.z = *(ushort*)&b2; o.w = *(ushort*)&b3;
        ((ushort4*)(nbf + (size_t)row * D_SZ))[lane] = o;
    }
}

// ---------------- helpers ---------------------------------------------------
__device__ __forceinline__ void decode_tile(int tb, int& i0, int& j0, bool& diag) {
    int bj = (int)((sqrtf(8.0f * tb + 1.0f) - 1.0f) * 0.5f);
    while ((bj + 1) * (bj + 2) / 2 <= tb) ++bj;
    while (bj * (bj + 1) / 2 > tb) --bj;
    const int bi = tb - bj * (bj + 1) / 2;
    i0 = bi * 128; j0 = bj * 128; diag = (bi == bj);
}

// async global->LDS DMA, 16 B per lane. LDS dest = wave-uniform base +
// lane*16 (linear); swizzle lives in the per-lane GLOBAL address (c8s).
__device__ __forceinline__ void gload16(const ushort* g, ushort* l) {
    __builtin_amdgcn_global_load_lds(
        (const __attribute__((address_space(1))) unsigned int*)g,
        (__attribute__((address_space(3))) unsigned int*)l,
        16, 0, 0);
}

// Issue one k64-stage of A+B staging as 8 DMAs per wave.
// Lane pattern identical to the proven reg-staged path: source row q*8+r,
// swizzled chunk c8s; LDS row wave*32+q*8+(lane>>3), slot lane&7 holds
// source chunk (lane&7)^r (un-swizzled at read time).
__device__ __forceinline__ void issue_stage(ushort* bA,
                                            const ushort* __restrict__ N,
                                            int i0, int j0, int k0,
                                            int wave, int r, int c8s) {
    ushort* bB = bA + 8192;
    const ushort* gA = N + (size_t)(i0 + wave * 32) * D_SZ + k0;
    const ushort* gB = N + (size_t)(j0 + wave * 32) * D_SZ + k0;
    #pragma unroll
    for (int q = 0; q < 4; ++q) {
        gload16(gA + (size_t)(q * 8 + r) * D_SZ + c8s, bA + (wave * 32 + q * 8) * 64);
        gload16(gB + (size_t)(q * 8 + r) * D_SZ + c8s, bB + (wave * 32 + q * 8) * 64);
    }
}

// ---------------- fused sim: DMA-staged pipeline, persistent tiles ---------
// Per stage: vmcnt(0) [stage-k DMAs landed; issued one full stage earlier]
// -> barrier -> issue DMA k+1 into other buffer [WAR-safe: its readers were
// stage k-1, pre-barrier] -> ds_read + MFMA on stage k. No VGPR staging, no
// ds_write. Epilogue partials live in buf1 region (buf0 holds next-tile
// prefetch in flight).
__global__ __launch_bounds__(256) void sim_kernel(const ushort* __restrict__ N,
                                                  const int* __restrict__ ids,
                                                  float* __restrict__ all_sum,
                                                  float* __restrict__ pos_sum) {
    __shared__ ushort smem[4 * 128 * 64];   // A0|B0|A1|B1, 16 KB each

    const int t    = threadIdx.x;
    const int wave = t >> 6, lane = t & 63;
    const int wy   = wave >> 1, wx = wave & 1;
    const int r    = lane >> 3;                     // 0..7 sub-row
    const int c8s  = ((lane & 7) ^ r) * 8;          // swizzled source chunk
    const int myc  = lane & 15;

    int tb = blockIdx.x;
    int i0, j0; bool diag;
    decode_tile(tb, i0, j0, diag);

    issue_stage(smem, N, i0, j0, 0, wave, r, c8s);  // prologue: stage 0 -> buf0

    while (true) {
        const int ntb = tb + GRID_SIM;
        const bool have_next = (ntb < NTILES);
        int ni0 = i0, nj0 = j0; bool ndiag = diag;
        if (have_next) decode_tile(ntb, ni0, nj0, ndiag);

        f32x4 acc[4][4];
        #pragma unroll
        for (int mi = 0; mi < 4; ++mi)
            #pragma unroll
            for (int ni = 0; ni < 4; ++ni)
                acc[mi][ni] = (f32x4){0.f, 0.f, 0.f, 0.f};

        #pragma unroll
        for (int kk = 0; kk < 4; ++kk) {
            ushort* bA = smem + (kk & 1) * 16384;          // read buffer
            ushort* bW = smem + ((kk + 1) & 1) * 16384;    // write buffer
            ushort* bB = bA + 8192;

            asm volatile("s_waitcnt vmcnt(0)" ::: "memory");  // stage-k DMAs landed
            __syncthreads();
            if (kk < 3)           issue_stage(bW, N, i0, j0, (kk + 1) * 64, wave, r, c8s);
            else if (have_next)   issue_stage(bW, N, ni0, nj0, 0, wave, r, c8s);

            #pragma unroll
            for (int ks = 0; ks < 2; ++ks) {
                const int C = ks * 4 + (lane >> 4);     // k-chunk index 0..7
                const int slot = (C ^ (lane & 7)) * 8;  // un-swizzle
                s16x8 af[4], bf[4];
                #pragma unroll
                for (int mi = 0; mi < 4; ++mi)
                    af[mi] = *(const s16x8*)&bA[(wy * 64 + mi * 16 + (lane & 15)) * 64 + slot];
                #pragma unroll
                for (int ni = 0; ni < 4; ++ni)
                    bf[ni] = *(const s16x8*)&bB[(wx * 64 + ni * 16 + (lane & 15)) * 64 + slot];
                #pragma unroll
                for (int mi = 0; mi < 4; ++mi)
                    #pragma unroll
                    for (int ni = 0; ni < 4; ++ni)
                        acc[mi][ni] = __builtin_amdgcn_mfma_f32_16x16x32_bf16(
                            af[mi], bf[ni], acc[mi][ni], 0, 0, 0);
            }
        }

        // ---- epilogue.  C/D map: col=lane&15, row=(lane>>4)*4+reg ----
        // Partials live in buf1 region (A1=rowAll, B1=rowPos). buf1 was read
        // at stage kk=3 -> barrier below separates. buf0 holds next-tile DMA.
        __syncthreads();
        float* rowAllPart = (float*)&smem[16384];    // [128][32]
        float* rowPosPart = (float*)&smem[24576];    // [128][32]

        int idc[4];
        #pragma unroll
        for (int ni = 0; ni < 4; ++ni)
            idc[ni] = ids[j0 + wx * 64 + ni * 16 + myc];

        float cAll[4] = {0.f, 0.f, 0.f, 0.f};
        float cPos[4] = {0.f, 0.f, 0.f, 0.f};

        #pragma unroll
        for (int mi = 0; mi < 4; ++mi) {
            float rAll[4] = {0.f, 0.f, 0.f, 0.f};
            float rPos[4] = {0.f, 0.f, 0.f, 0.f};
            const int rbase = wy * 64 + mi * 16 + (lane >> 4) * 4;
            const int4 idr  = *(const int4*)&ids[i0 + rbase];
            #pragma unroll
            for (int ni = 0; ni < 4; ++ni) {
                const int cloc = wx * 64 + ni * 16 + myc;
                #pragma unroll
                for (int rg = 0; rg < 4; ++rg) {
                    const int lr = rbase + rg;
                    float e = __builtin_amdgcn_exp2f(acc[mi][ni][rg]);
                    if (diag && lr == cloc) e = 0.0f;        // diagonal element
                    rAll[rg] += e; cAll[ni] += e;
                    const int idrv = (rg == 0) ? idr.x : (rg == 1) ? idr.y
                                   : (rg == 2) ? idr.z : idr.w;
                    if (idrv == idc[ni]) { rPos[rg] += e; cPos[ni] += e; }
                }
            }
            #pragma unroll
            for (int rg = 0; rg < 4; ++rg) {
                rowAllPart[(rbase + rg) * 32 + wx * 16 + myc] = rAll[rg];
                rowPosPart[(rbase + rg) * 32 + wx * 16 + myc] = rPos[rg];
            }
        }

        // column sums -> rows j (off-diagonal tiles only; symmetry)
        if (!diag) {
            #pragma unroll
            for (int ni = 0; ni < 4; ++ni) {
                cAll[ni] += __shfl_xor(cAll[ni], 16, 64);
                cAll[ni] += __shfl_xor(cAll[ni], 32, 64);
                cPos[ni] += __shfl_xor(cPos[ni], 16, 64);
                cPos[ni] += __shfl_xor(cPos[ni], 32, 64);
            }
            if (lane < 16) {
                #pragma unroll
                for (int ni = 0; ni < 4; ++ni) {
                    const int gc = j0 + wx * 64 + ni * 16 + lane;
                    atomicAdd(&all_sum[gc], cAll[ni]);
                    if (cPos[ni] != 0.0f) atomicAdd(&pos_sum[gc], cPos[ni]);
                }
            }
        }

        __syncthreads();
        // row partial reduce: thread t -> (row = t&127, array = t>>7)
        {
            const int row = t & 127;
            const float* src = (t >= 128) ? rowPosPart : rowAllPart;
            float s = 0.0f;
            #pragma unroll
            for (int k8 = 0; k8 < 8; ++k8) {
                const int chunk = (k8 + (row & 7)) & 7;
                const float4 v = *(const float4*)&src[row * 32 + chunk * 4];
                s += v.x + v.y + v.z + v.w;
            }
            float* dst = (t >= 128) ? pos_sum : all_sum;
            atomicAdd(&dst[i0 + row], s);
        }
        // next loop iteration's vmcnt(0)+barrier separates these reads from
        // the kk=0 DMA issue into buf1.

        if (!have_next) break;
        tb = ntb; i0 = ni0; j0 = nj0; diag = ndiag;
    }
}

// ---------------- final scalar reduce ----------------
__global__ __launch_bounds__(256) void loss_kernel(const float* __restrict__ all_sum,
                                                   const float* __restrict__ pos_sum,
                                                   float* __restrict__ out) {
    float loss = 0.0f, cnt = 0.0f;
    for (int i = threadIdx.x; i < B_SZ; i += 256) {
        float p = pos_sum[i], a = all_sum[i];
        if (p > 0.0f) { loss += logf(a) - logf(p); cnt += 1.0f; }
    }
    #pragma unroll
    for (int m = 1; m < 64; m <<= 1) {
        loss += __shfl_xor(loss, m, 64);
        cnt  += __shfl_xor(cnt, m, 64);
    }
    __shared__ float sl[4], sc[4];
    int wave = threadIdx.x >> 6, lane = threadIdx.x & 63;
    if (lane == 0) { sl[wave] = loss; sc[wave] = cnt; }
    __syncthreads();
    if (threadIdx.x == 0) {
        float L = sl[0] + sl[1] + sl[2] + sl[3];
        float C = sc[0] + sc[1] + sc[2] + sc[3];
        out[0] = L / fmaxf(C, 1.0f);
    }
}

extern "C" void kernel_launch(void* const* d_in, const int* in_sizes, int n_in,
                              void* d_out, int out_size, void* d_ws, size_t ws_size,
                              hipStream_t stream) {
    const float* emb = (const float*)d_in[0];
    const int*   ids = (const int*)d_in[1];
    float*       out = (float*)d_out;

    float*  all_sum = (float*)d_ws;
    float*  pos_sum = all_sum + B_SZ;
    ushort* nbf     = (ushort*)((char*)d_ws + 65536);   // 8192*256 bf16 = 4 MB

    norm_kernel<<<256, 256, 0, stream>>>(emb, nbf, all_sum);
    sim_kernel<<<GRID_SIM, 256, 0, stream>>>(nbf, ids, all_sum, pos_sum);
    loss_kernel<<<1, 256, 0, stream>>>(all_sum, pos_sum, out);
}